// Round 2
// baseline (1983.828 us; speedup 1.0000x reference)
//
#include <hip/hip_runtime.h>

// ---------------- problem dims ----------------
#define TT   512
#define DIN  1024
#define DH   2048
#define DOUT 1024

// ---------------- launch shape ----------------
#define NWG   256    // WGs 0..127: h1 chain (+epilogue); 128..255: h2 chain
#define HALF  128
#define NTHR  512    // 8 waves; each wave owns 2 h-rows of its chain
#define NSLOT (TT + 1)

typedef unsigned int u32;
typedef unsigned long long u64;

// Records: one u64 per h element per step {epoch (hi 32) | f32 bits (lo 32)}.
// Slot t is unique per step -> no ring reuse, no ABA, deadlock-free DAG.
//
// NEW (this round): per-(slot, producer-WG) FLAGS. Consumers spin on 128
// u32 flags (512 B) instead of 16 KB of records -> ~30x less spin traffic
// hammering the L3 while waiting. Records are then bulk-loaded ONCE via
// plain cached 16B loads and epoch-VERIFIED (flags and records are
// unordered relaxed stores; the atomic-load fallback both catches
// stragglers and bypasses any stale L2 line). Epoch base bump per launch
// makes stale flags/records from prior runs unmatchable -> no init pass.
__device__ u64 gR1[NSLOT * DH];     // h1 records
__device__ u64 gR2[NSLOT * DH];     // h2 records
__device__ u32 gF1[NSLOT * HALF];   // h1 per-WG flags (value = epoch)
__device__ u32 gF2[NSLOT * HALF];   // h2 per-WG flags
__device__ u32 g_epoch_base;        // zero at module load; +=NSLOT per run

__device__ __forceinline__ float dot4(float4 a, float4 b) {
  return a.x * b.x + a.y * b.y + a.z * b.z + a.w * b.w;
}
__device__ __forceinline__ float wave_sum(float v) {
  #pragma unroll
  for (int off = 32; off > 0; off >>= 1) v += __shfl_down(v, off, 64);
  return v; // lane 0 holds the sum
}
__device__ __forceinline__ u64 ld_rec(const u64* p) {
  return __hip_atomic_load((u64*)p, __ATOMIC_RELAXED, __HIP_MEMORY_SCOPE_AGENT);
}
__device__ __forceinline__ void st_rec(u64* p, u64 v) {
  __hip_atomic_store(p, v, __ATOMIC_RELAXED, __HIP_MEMORY_SCOPE_AGENT);
}
__device__ __forceinline__ u32 ld_flag(const u32* p) {
  return __hip_atomic_load((u32*)p, __ATOMIC_RELAXED, __HIP_MEMORY_SCOPE_AGENT);
}
__device__ __forceinline__ void st_flag(u32* p, u32 v) {
  __hip_atomic_store(p, v, __ATOMIC_RELAXED, __HIP_MEMORY_SCOPE_AGENT);
}
__device__ __forceinline__ u64 pack(float h, u32 ep) {
  return ((u64)ep << 32) | (u64)__float_as_uint(h);
}
// Fast tanh, ~3 ulp, branch-free: only lane 0 (2x per wave per step).
__device__ __forceinline__ float fast_tanh(float x) {
  float xc = fminf(fmaxf(x, -9.0f), 9.0f);
  float e  = __expf(2.0f * xc);
  return (e - 1.0f) * __frcp_rn(e + 1.0f);
}

// Spin on one slot's 128 per-WG flags. Only wave 0 polls (2 flags/lane,
// pending-only); other waves park at the barrier. Ends with syncthreads,
// which also compiler-fences the speculative record loads that follow.
__device__ __forceinline__ void poll_flags(const u32* f, u32 ep, int tid) {
  if (tid < 64) {
    bool d0 = false, d1 = false;
    for (;;) {
      if (!d0) d0 = (ld_flag(f + tid     ) == ep);
      if (!d1) d1 = (ld_flag(f + tid + 64) == ep);
      if (d0 & d1) break;
      __builtin_amdgcn_s_sleep(1);
    }
  }
  __syncthreads();
}
// Dual-slot flag wait (h2 chain: h1[t] and h2[t-1]).
__device__ __forceinline__ void poll_flags2(const u32* fA, u32 epA,
                                            const u32* fB, u32 epB, int tid) {
  if (tid < 64) {
    bool a0 = false, a1 = false, b0 = false, b1 = false;
    for (;;) {
      if (!a0) a0 = (ld_flag(fA + tid     ) == epA);
      if (!a1) a1 = (ld_flag(fA + tid + 64) == epA);
      if (!b0) b0 = (ld_flag(fB + tid     ) == epB);
      if (!b1) b1 = (ld_flag(fB + tid + 64) == epB);
      if (a0 & a1 & b0 & b1) break;
      __builtin_amdgcn_s_sleep(1);
    }
  }
  __syncthreads();
}

// Post-flag bulk fetch: thread tid owns rows 4*tid..4*tid+3 (32 B
// contiguous -> two dwordx4, perfectly coalesced). Epoch-verify each u64;
// rare stragglers (or stale L2 lines) are re-fetched with sc1 atomic loads.
__device__ __forceinline__ void bulk_stage(const u64* rec, u32 ep,
                                           float* lds, int tid) {
  const u64* p = rec + 4 * (size_t)tid;
  const ulonglong2* q = (const ulonglong2*)p;
  ulonglong2 q0 = q[0], q1 = q[1];
  u64 v0 = q0.x, v1 = q0.y, v2 = q1.x, v3 = q1.y;
  bool d0 = ((u32)(v0 >> 32) == ep), d1 = ((u32)(v1 >> 32) == ep);
  bool d2 = ((u32)(v2 >> 32) == ep), d3 = ((u32)(v3 >> 32) == ep);
  while (!(d0 & d1 & d2 & d3)) {
    __builtin_amdgcn_s_sleep(1);
    if (!d0) { v0 = ld_rec(p + 0); d0 = ((u32)(v0 >> 32) == ep); }
    if (!d1) { v1 = ld_rec(p + 1); d1 = ((u32)(v1 >> 32) == ep); }
    if (!d2) { v2 = ld_rec(p + 2); d2 = ((u32)(v2 >> 32) == ep); }
    if (!d3) { v3 = ld_rec(p + 3); d3 = ((u32)(v3 >> 32) == ep); }
  }
  ((float4*)lds)[tid] = make_float4(
      __uint_as_float((u32)v0), __uint_as_float((u32)v1),
      __uint_as_float((u32)v2), __uint_as_float((u32)v3));
}

// Two-slot bulk fetch with all 4 dwordx4 issued before any wait (one RT,
// not two, for the h2 chain's dual dependency).
__device__ __forceinline__ void bulk_stage2(const u64* recA, u32 epA,
                                            const u64* recB, u32 epB,
                                            float* ldsA, float* ldsB, int tid) {
  const u64* pa = recA + 4 * (size_t)tid;
  const u64* pb = recB + 4 * (size_t)tid;
  const ulonglong2* qa = (const ulonglong2*)pa;
  const ulonglong2* qb = (const ulonglong2*)pb;
  ulonglong2 a01 = qa[0], a23 = qa[1], b01 = qb[0], b23 = qb[1];
  u64 a0 = a01.x, a1 = a01.y, a2 = a23.x, a3 = a23.y;
  u64 b0 = b01.x, b1 = b01.y, b2 = b23.x, b3 = b23.y;
  bool da0 = ((u32)(a0 >> 32) == epA), da1 = ((u32)(a1 >> 32) == epA);
  bool da2 = ((u32)(a2 >> 32) == epA), da3 = ((u32)(a3 >> 32) == epA);
  bool db0 = ((u32)(b0 >> 32) == epB), db1 = ((u32)(b1 >> 32) == epB);
  bool db2 = ((u32)(b2 >> 32) == epB), db3 = ((u32)(b3 >> 32) == epB);
  while (!(da0 & da1 & da2 & da3 & db0 & db1 & db2 & db3)) {
    __builtin_amdgcn_s_sleep(1);
    if (!da0) { a0 = ld_rec(pa + 0); da0 = ((u32)(a0 >> 32) == epA); }
    if (!da1) { a1 = ld_rec(pa + 1); da1 = ((u32)(a1 >> 32) == epA); }
    if (!da2) { a2 = ld_rec(pa + 2); da2 = ((u32)(a2 >> 32) == epA); }
    if (!da3) { a3 = ld_rec(pa + 3); da3 = ((u32)(a3 >> 32) == epA); }
    if (!db0) { b0 = ld_rec(pb + 0); db0 = ((u32)(b0 >> 32) == epB); }
    if (!db1) { b1 = ld_rec(pb + 1); db1 = ((u32)(b1 >> 32) == epB); }
    if (!db2) { b2 = ld_rec(pb + 2); db2 = ((u32)(b2 >> 32) == epB); }
    if (!db3) { b3 = ld_rec(pb + 3); db3 = ((u32)(b3 >> 32) == epB); }
  }
  ((float4*)ldsA)[tid] = make_float4(
      __uint_as_float((u32)a0), __uint_as_float((u32)a1),
      __uint_as_float((u32)a2), __uint_as_float((u32)a3));
  ((float4*)ldsB)[tid] = make_float4(
      __uint_as_float((u32)b0), __uint_as_float((u32)b1),
      __uint_as_float((u32)b2), __uint_as_float((u32)b3));
}

// Advance the epoch base past all epochs any previous run could have stored.
__global__ void bump_kernel() {
  if (threadIdx.x == 0)
    __hip_atomic_fetch_add(&g_epoch_base, (u32)NSLOT,
                           __ATOMIC_RELAXED, __HIP_MEMORY_SCOPE_AGENT);
}

__global__ __launch_bounds__(NTHR, 2)
void rnn2_kernel(const float* __restrict__ X,
                 const float* __restrict__ Wa, const float* __restrict__ ba,
                 const float* __restrict__ Wb, const float* __restrict__ bb,
                 const float* __restrict__ Wc, const float* __restrict__ bc,
                 const float* __restrict__ Wd, const float* __restrict__ bd,
                 const float* __restrict__ Wo, const float* __restrict__ bo,
                 float* __restrict__ out)
{
  const int g   = blockIdx.x;
  const int tid = threadIdx.x;
  const int w   = tid >> 6;   // wave
  const int l   = tid & 63;   // lane

  const u32 eb = __hip_atomic_load(&g_epoch_base, __ATOMIC_RELAXED,
                                   __HIP_MEMORY_SCOPE_AGENT);

  __shared__ float sA[2][DH];
  __shared__ float sB[2][DH];
  // Intra-WG publish counter (per step parity). The wave whose lane 0 sees
  // old==7 is the last publisher; it resets the counter and fires the
  // per-WG flag — no extra barrier on the publish path. Parity reuse is
  // gated by two flag round-trips, so reset races are impossible.
  __shared__ u32 sDone[2];
  if (tid == 0) { sDone[0] = 0u; sDone[1] = 0u; }
  __syncthreads();

  if (g < HALF) {
    // ================= h1 chain (+ output epilogue) =================
    const int r0 = g * 16 + 2 * w, r1 = r0 + 1;   // my two h1 rows
    float4 wA0[4], wA1[4], wB0[8], wB1[8], wO[8];
    {
      const float4* p0 = (const float4*)(Wa + (size_t)r0 * DIN);
      const float4* p1 = (const float4*)(Wa + (size_t)r1 * DIN);
      #pragma unroll
      for (int j = 0; j < 4; ++j) { wA0[j] = p0[l + 64 * j]; wA1[j] = p1[l + 64 * j]; }
    }
    {
      const float4* p0 = (const float4*)(Wb + (size_t)r0 * DH);
      const float4* p1 = (const float4*)(Wb + (size_t)r1 * DH);
      #pragma unroll
      for (int j = 0; j < 8; ++j) { wB0[j] = p0[l + 64 * j]; wB1[j] = p1[l + 64 * j]; }
    }
    const int orow = g * 8 + w;                   // my output row
    {
      const float4* p = (const float4*)(Wo + (size_t)orow * DH);
      #pragma unroll
      for (int j = 0; j < 8; ++j) wO[j] = p[l + 64 * j];
    }
    const float b1_0 = ba[r0] + bb[r0];
    const float b1_1 = ba[r1] + bb[r1];
    const float bo_r = bo[orow];

    for (int t = 1; t <= TT; ++t) {
      // A.x[t-1]: no cross-WG dependency — compute before the wait
      float a0 = 0.f, a1 = 0.f;
      {
        const float4* px = (const float4*)(X + (size_t)(t - 1) * DIN);
        #pragma unroll
        for (int j = 0; j < 4; ++j) {
          float4 x4 = px[l + 64 * j];
          a0 += dot4(wA0[j], x4);
          a1 += dot4(wA1[j], x4);
        }
      }
      if (t > 1) {
        const u32 epp = eb + (u32)(t - 1);
        float* buf = sA[(t - 1) & 1];
        poll_flags(gF1 + (size_t)(t - 1) * HALF, epp, tid);   // barrier inside
        bulk_stage(gR1 + (size_t)(t - 1) * DH, epp, buf, tid);
        __syncthreads();
        const float4* ph = (const float4*)buf;
        #pragma unroll
        for (int j = 0; j < 8; ++j) {
          float4 h4 = ph[l + 64 * j];
          a0 += dot4(wB0[j], h4);
          a1 += dot4(wB1[j], h4);
        }
      }
      a0 = wave_sum(a0); a1 = wave_sum(a1);
      if (l == 0) {   // publish records, then (last wave only) the WG flag
        const u32 ept = eb + (u32)t;
        u64* dst = gR1 + (size_t)t * DH;
        st_rec(dst + r0, pack(fast_tanh(a0 + b1_0), ept));
        st_rec(dst + r1, pack(fast_tanh(a1 + b1_1), ept));
        u32 old = atomicAdd(&sDone[t & 1], 1u);
        if (old == 7u) {
          sDone[t & 1] = 0u;
          st_flag(&gF1[(size_t)t * HALF + g], ept);
        }
      }
    }

    // ---- epilogue: out = Wo . h2[TT] + bo (1 row per wave) ----
    {
      const u32 epT = eb + (u32)TT;
      poll_flags(gF2 + (size_t)TT * HALF, epT, tid);
      bulk_stage(gR2 + (size_t)TT * DH, epT, sA[0], tid);
      __syncthreads();
      const float4* ph = (const float4*)sA[0];
      float acc = 0.f;
      #pragma unroll
      for (int j = 0; j < 8; ++j) acc += dot4(wO[j], ph[l + 64 * j]);
      acc = wave_sum(acc);
      if (l == 0) out[orow] = acc + bo_r;
    }
  } else {
    // ========================= h2 chain =========================
    const int gg = g - HALF;
    const int r0 = gg * 16 + 2 * w, r1 = r0 + 1;  // my two h2 rows
    float4 wC0[8], wC1[8], wD0[8], wD1[8];
    {
      const float4* p0 = (const float4*)(Wc + (size_t)r0 * DH);
      const float4* p1 = (const float4*)(Wc + (size_t)r1 * DH);
      #pragma unroll
      for (int j = 0; j < 8; ++j) { wC0[j] = p0[l + 64 * j]; wC1[j] = p1[l + 64 * j]; }
    }
    {
      const float4* p0 = (const float4*)(Wd + (size_t)r0 * DH);
      const float4* p1 = (const float4*)(Wd + (size_t)r1 * DH);
      #pragma unroll
      for (int j = 0; j < 8; ++j) { wD0[j] = p0[l + 64 * j]; wD1[j] = p1[l + 64 * j]; }
    }
    const float b2_0 = bc[r0] + bd[r0];
    const float b2_1 = bc[r1] + bd[r1];

    for (int t = 1; t <= TT; ++t) {
      float* bufA = sA[t & 1];
      float* bufB = sB[t & 1];
      const u32 ept = eb + (u32)t;
      if (t > 1) {
        const u32 epp = eb + (u32)(t - 1);
        poll_flags2(gF1 + (size_t)t * HALF, ept,
                    gF2 + (size_t)(t - 1) * HALF, epp, tid);
        bulk_stage2(gR1 + (size_t)t * DH, ept,
                    gR2 + (size_t)(t - 1) * DH, epp, bufA, bufB, tid);
      } else {
        poll_flags(gF1 + (size_t)1 * HALF, eb + 1u, tid);
        bulk_stage(gR1 + (size_t)1 * DH, eb + 1u, bufA, tid);
      }
      __syncthreads();

      float a0 = 0.f, a1 = 0.f;
      {
        const float4* ph = (const float4*)bufA;
        #pragma unroll
        for (int j = 0; j < 8; ++j) {
          float4 h4 = ph[l + 64 * j];
          a0 += dot4(wC0[j], h4);
          a1 += dot4(wC1[j], h4);
        }
      }
      if (t > 1) {
        const float4* ph = (const float4*)bufB;
        #pragma unroll
        for (int j = 0; j < 8; ++j) {
          float4 h4 = ph[l + 64 * j];
          a0 += dot4(wD0[j], h4);
          a1 += dot4(wD1[j], h4);
        }
      }
      a0 = wave_sum(a0); a1 = wave_sum(a1);
      if (l == 0) {
        u64* dst = gR2 + (size_t)t * DH;
        st_rec(dst + r0, pack(fast_tanh(a0 + b2_0), ept));
        st_rec(dst + r1, pack(fast_tanh(a1 + b2_1), ept));
        u32 old = atomicAdd(&sDone[t & 1], 1u);
        if (old == 7u) {
          sDone[t & 1] = 0u;
          st_flag(&gF2[(size_t)t * HALF + gg], ept);
        }
      }
    }
  }
}

extern "C" void kernel_launch(void* const* d_in, const int* in_sizes, int n_in,
                              void* d_out, int out_size, void* d_ws, size_t ws_size,
                              hipStream_t stream)
{
  (void)in_sizes; (void)n_in; (void)out_size; (void)d_ws; (void)ws_size;

  const float* X  = (const float*)d_in[0];
  const float* Wa = (const float*)d_in[1];   // W_i2h1 [H][IN]
  const float* ba = (const float*)d_in[2];
  const float* Wb = (const float*)d_in[3];   // W_h2h1 [H][H]
  const float* bb = (const float*)d_in[4];
  // d_in[5], d_in[6]: W_h2o1 / b_h2o1 — dead code in the reference
  const float* Wc = (const float*)d_in[7];   // W_i2h2 [H][H]
  const float* bc = (const float*)d_in[8];
  const float* Wd = (const float*)d_in[9];   // W_h2h2 [H][H]
  const float* bd = (const float*)d_in[10];
  const float* Wo = (const float*)d_in[11];  // W_h2o2 [OUT][H]
  const float* bo = (const float*)d_in[12];
  float* out = (float*)d_out;

  bump_kernel<<<dim3(1), dim3(64), 0, stream>>>();

  void* args[] = { &X, &Wa, &ba, &Wb, &bb, &Wc, &bc, &Wd, &bd, &Wo, &bo, &out };
  (void)hipLaunchCooperativeKernel((void*)rnn2_kernel, dim3(NWG), dim3(NTHR),
                                   args, 0, stream);
}